// Round 11
// baseline (195.660 us; speedup 1.0000x reference)
//
#include <hip/hip_runtime.h>
#include <hip/hip_bf16.h>

// MicroHeadAttention on MI355X (gfx950). fp32 in / fp32 out, bf16 MFMA internally.
// Pipeline: [cvt fp32->bf16] -> [QKV gemm 256x256 8-phase, Q pre-scaled by KL,
//            V written directly transposed via LDS repack (transpose_v fused)]
//        -> [attn v15: 32x32 MFMA paired-wave key-split, QBLK=128, 8 waves]
//        -> [out-proj gemm 128x64].
// Scramble (derived from the proven transpose_v read side):
//   C[m][n] of the V gemm = V(b=m>>11, mh=(m>>8)&7, g=n>>9,
//                             pos=((m&255)<<3)|((n&511)>>6), d=n&63).
// Workspace (>=64 MB; harness poison fill shows ~256 MiB):
//   Wb(8) | xb(8) | Qb(8, reused as Cb) | Kb(8) | VT(8 @ +32MB).
typedef unsigned short ushortT;
typedef __attribute__((ext_vector_type(8))) short short8;
typedef __attribute__((ext_vector_type(4))) float floatx4;
typedef __attribute__((ext_vector_type(16))) float floatx16;
typedef __attribute__((ext_vector_type(2))) unsigned int uintx2;

__device__ inline ushortT f2bf(float f) {
    union { float f; unsigned int i; } v; v.f = f;
    unsigned int x = v.i;
    return (ushortT)((x + 0x7fffu + ((x >> 16) & 1u)) >> 16);  // RNE
}

__device__ inline void gl_lds16(const ushortT* g, ushortT* lds) {
    __builtin_amdgcn_global_load_lds(
        (const __attribute__((address_space(1))) unsigned int*)g,
        (__attribute__((address_space(3))) unsigned int*)lds, 16, 0, 0);
}

// ---------------------------------------------------------------------------
// cvt: x (4M f32) -> xb bf16; Wq,Wk,Wv,Wo (1M each) -> Wb stacked bf16.
// ---------------------------------------------------------------------------
__global__ __launch_bounds__(256) void cvt_bf16(
    const float* __restrict__ x,
    const float* __restrict__ Wq, const float* __restrict__ Wk,
    const float* __restrict__ Wv, const float* __restrict__ Wo,
    ushortT* __restrict__ xb, ushortT* __restrict__ Wb)
{
    const unsigned tid = blockIdx.x * 256 + threadIdx.x;
    const size_t e = (size_t)tid * 8;
    const float* src;
    ushortT* dst;
    size_t off;
    if (e < (size_t)(4u << 20)) { src = x; dst = xb; off = e; }
    else {
        const size_t r = e - (size_t)(4u << 20);
        const int wsel = (int)(r >> 20);
        off = r & 0xFFFFFu;
        src = (wsel == 0) ? Wq : (wsel == 1) ? Wk : (wsel == 2) ? Wv : Wo;
        dst = Wb + ((size_t)wsel << 20);
    }
    const float4 f0 = ((const float4*)(src + off))[0];
    const float4 f1 = ((const float4*)(src + off))[1];
    union { __hip_bfloat162 h[4]; uint4 u; } pk;
    pk.h[0] = __float22bfloat162_rn(float2{f0.x, f0.y});
    pk.h[1] = __float22bfloat162_rn(float2{f0.z, f0.w});
    pk.h[2] = __float22bfloat162_rn(float2{f1.x, f1.y});
    pk.h[3] = __float22bfloat162_rn(float2{f1.z, f1.w});
    *(uint4*)(dst + off) = pk.u;
}

// ---------------------------------------------------------------------------
// gemm_qkv_8p: C[m,n] = (sum_k A[m,k]*W[n,k] + bias[n]) * oscale, bf16 out.
// 256x256 tile, BK=64, 512 thr, T3+T4+T5 schedule, 128 KB LDS.
// mat==2 (V): epilogue repacks acc via LDS Lv[d(64)][pi(1024)], pi=ml*4+wn,
// then streams uint2 runs to VT[slice][d][pos] (transpose_v fused).
// ---------------------------------------------------------------------------
__global__ __launch_bounds__(512, 2) void gemm_qkv_8p(
    const ushortT* __restrict__ A, const ushortT* __restrict__ Wst,
    const float* __restrict__ b0, const float* __restrict__ b1, const float* __restrict__ b2,
    ushortT* __restrict__ O0, ushortT* __restrict__ O1, ushortT* __restrict__ VT)
{
    __shared__ __align__(16) ushortT sm[65536];   // 128 KB

    const int t = threadIdx.x;
    const int bid = blockIdx.x;                    // 0..191
    const int wg = (bid & 7) * 24 + (bid >> 3);    // bijective XCD chunk swizzle
    const int mt = wg / 12;                        // 0..15
    const int nt = wg - mt * 12;                   // 0..11 (3 mats x 4 tiles)
    const int m0 = mt * 256;
    const int mat = nt >> 2;
    const int n0 = (nt & 3) * 256;
    const ushortT* W = Wst + ((size_t)mat << 20);
    const float* bias = (mat == 0) ? b0 : (mat == 1) ? b1 : b2;
    ushortT* Out     = (mat == 0) ? O0 : O1;       // mat 2 uses the VT path
    const float oscale = (mat == 0) ? 0.18033688f : 1.0f;   // 0.125*log2(e)

    const int w = t >> 6, lane = t & 63;
    const int wm = w >> 2, wn = w & 3;             // 2 x 4 wave grid
    const int col16 = lane & 15, quad = lane >> 4;
    const int c7 = col16 & 7;

    // fragment read offsets (elements); row&7 == col16&7 for all frag rows
    const int ko[2] = { ((0 + quad) ^ c7) << 3, ((4 + quad) ^ c7) << 3 };
    const int xbase = (wm * 128 + col16) * 64;     // x rows (MFMA B-operand)
    const int wbase = (wn * 64 + col16) * 64;      // W rows (MFMA A-operand)

    // staging: cid = q*512 + t -> row q*64+(t>>3), chunk t&7, sch = chunk^(row&7)
    const int trow = t >> 3;
    const int sch = (t & 7) ^ (trow & 7);
    const ushortT* gA[4]; const ushortT* gB[4];
    #pragma unroll
    for (int q = 0; q < 4; q++) {
        gA[q] = A + (size_t)(m0 + q * 64 + trow) * 1024 + sch * 8;
        gB[q] = W + (size_t)(n0 + q * 64 + trow) * 1024 + sch * 8;
    }
    const int dst0 = (w << 6) * 8;                 // wave-uniform LDS dest base

    floatx4 acc[8][4];
    #pragma unroll
    for (int i = 0; i < 8; i++)
        #pragma unroll
        for (int j = 0; j < 4; j++) acc[i][j] = (floatx4)0.0f;

    auto issue8 = [&](const int ab, const int bb) {
        #pragma unroll
        for (int q = 0; q < 4; q++) {
            gl_lds16(gA[q], sm + ab + dst0 + q * 4096);
            gl_lds16(gB[q], sm + bb + dst0 + q * 4096);
            gA[q] += 64; gB[q] += 64;
        }
    };

    auto group = [&](const int ab, const int bb) {   // 4 phases over one K-tile
        short8 bw[4];
        #pragma unroll
        for (int ks = 0; ks < 2; ks++) {
            #pragma unroll
            for (int mh = 0; mh < 2; mh++) {
                short8 bx[4];
                if (mh == 0) {
                    #pragma unroll
                    for (int nf = 0; nf < 4; nf++)
                        bw[nf] = *(const short8*)(sm + bb + wbase + nf * 1024 + ko[ks]);
                }
                #pragma unroll
                for (int j = 0; j < 4; j++)
                    bx[j] = *(const short8*)(sm + ab + xbase + (mh * 4 + j) * 1024 + ko[ks]);
                __builtin_amdgcn_s_barrier();
                __builtin_amdgcn_s_setprio(1);
                #pragma unroll
                for (int j = 0; j < 4; j++)
                    #pragma unroll
                    for (int nf = 0; nf < 4; nf++)
                        acc[mh * 4 + j][nf] = __builtin_amdgcn_mfma_f32_16x16x32_bf16(
                            bw[nf], bx[j], acc[mh * 4 + j][nf], 0, 0, 0);
                __builtin_amdgcn_s_setprio(0);
                __builtin_amdgcn_s_barrier();
            }
        }
    };

    issue8(0, 16384);            // tile 0 -> buf0
    issue8(32768, 49152);        // tile 1 -> buf1

    #pragma unroll 1
    for (int it = 0; it < 7; ++it) {
        asm volatile("s_waitcnt vmcnt(8)" ::: "memory");   // tile 2it landed
        __builtin_amdgcn_s_barrier();
        group(0, 16384);
        issue8(0, 16384);                                  // tile 2it+2 -> buf0
        asm volatile("s_waitcnt vmcnt(8)" ::: "memory");   // tile 2it+1 landed
        __builtin_amdgcn_s_barrier();
        group(32768, 49152);
        issue8(32768, 49152);                              // tile 2it+3 -> buf1
    }
    asm volatile("s_waitcnt vmcnt(8)" ::: "memory");       // tile 14 landed
    __builtin_amdgcn_s_barrier();
    group(0, 16384);
    asm volatile("s_waitcnt vmcnt(0)" ::: "memory");       // tile 15 landed
    __builtin_amdgcn_s_barrier();
    group(32768, 49152);

    if (mat != 2) {
        // epilogue: D[n via quad*4+r, m via col16] (swapped-operand layout)
        #pragma unroll
        for (int mf = 0; mf < 8; mf++) {
            const int m = m0 + wm * 128 + mf * 16 + col16;
            #pragma unroll
            for (int nf = 0; nf < 4; nf++) {
                const int nb = n0 + wn * 64 + nf * 16 + quad * 4;
                const float4 bv4 = *(const float4*)(bias + nb);
                const float v0 = (acc[mf][nf][0] + bv4.x) * oscale;
                const float v1 = (acc[mf][nf][1] + bv4.y) * oscale;
                const float v2 = (acc[mf][nf][2] + bv4.z) * oscale;
                const float v3 = (acc[mf][nf][3] + bv4.w) * oscale;
                union { __hip_bfloat162 h[2]; unsigned long long u; } pk2;
                pk2.h[0] = __float22bfloat162_rn(float2{v0, v1});
                pk2.h[1] = __float22bfloat162_rn(float2{v2, v3});
                *(unsigned long long*)(Out + (size_t)m * 1024 + nb) = pk2.u;
            }
        }
    } else {
        // V epilogue: acc -> LDS Lv[d][pi], pi = ml*4 + wn, then uint2 runs.
        __syncthreads();                           // LDS dead after K-loop
        #pragma unroll
        for (int mf = 0; mf < 8; mf++) {
            const int ml = wm * 128 + mf * 16 + col16;
            const int pib = ml * 4 + wn;
            #pragma unroll
            for (int nf = 0; nf < 4; nf++) {
                const int dbase = nf * 16 + quad * 4;
                const float4 bv4 = *(const float4*)(bias + n0 + wn * 64 + dbase);
                sm[(dbase + 0) * 1024 + pib] = f2bf(acc[mf][nf][0] + bv4.x);
                sm[(dbase + 1) * 1024 + pib] = f2bf(acc[mf][nf][1] + bv4.y);
                sm[(dbase + 2) * 1024 + pib] = f2bf(acc[mf][nf][2] + bv4.z);
                sm[(dbase + 3) * 1024 + pib] = f2bf(acc[mf][nf][3] + bv4.w);
            }
        }
        __syncthreads();
        const int b2 = mt >> 3, mhh = mt & 7, gg = n0 >> 9;
        const int p0 = (n0 & 511) >> 6;
        ushortT* vbase = VT + (size_t)((b2 * 2 + gg) * 8 + mhh) * 131072 + p0;
        #pragma unroll
        for (int v = 0; v < 32; v++) {
            const int e = v * 512 + t;             // 0..16383 run index
            const int d = e >> 8;                  // 0..63
            const int runml = e & 255;             // 0..255
            const uint2 val = *(const uint2*)(sm + d * 1024 + runml * 4);
            *(uint2*)(vbase + d * 2048 + runml * 8) = val;
        }
    }
}

// ---------------------------------------------------------------------------
// gemm_lds (out-proj): C[m,n] = sum_k A[m,k]*W[n,k] + bias[n]. Tile 128 x 64,
// BK=64, 4 waves 2x2, MFMA operands swapped -> vectorized stores.
// ---------------------------------------------------------------------------
template <bool OUT_F32, bool N64>
__global__ __launch_bounds__(256) void gemm_lds(
    const ushortT* __restrict__ A, const ushortT* __restrict__ Wst,
    const float* __restrict__ b0, const float* __restrict__ b1, const float* __restrict__ b2,
    void* __restrict__ O0, void* __restrict__ O1, void* __restrict__ O2)
{
    constexpr int NT = N64 ? 64 : 128;
    constexpr int NJ = N64 ? 2 : 4;
    constexpr int WQ = N64 ? 2 : 4;
    __shared__ __align__(16) ushortT As[128 * 64];
    __shared__ __align__(16) ushortT Bs[NT * 64];
    const int t = threadIdx.x;
    const int m0 = blockIdx.y * 128;
    const int n0g = blockIdx.x * NT;
    const int mat = n0g >> 10;
    const int n0 = n0g & 1023;
    const ushortT* W = Wst + ((size_t)mat << 20);
    const float* bias = (mat == 0) ? b0 : (mat == 1) ? b1 : b2;
    void* Out        = (mat == 0) ? O0 : (mat == 1) ? O1 : O2;

    const int w = t >> 6, lane = t & 63;
    const int wm = w >> 1, wn = w & 1;
    const int col16 = lane & 15, quad = lane >> 4;

    floatx4 acc[4][NJ];
    for (int i = 0; i < 4; i++)
        for (int j = 0; j < NJ; j++) acc[i][j] = (floatx4)0.0f;

    const int cid0 = w * (N64 ? 128 : 256) + lane;

    for (int k0 = 0; k0 < 1024; k0 += 64) {
        #pragma unroll
        for (int q = 0; q < 4; q++) {
            const int cid = w * 256 + q * 64 + lane;
            const int row = cid >> 3;
            const int sch = (cid & 7) ^ (row & 7);
            gl_lds16(A + (size_t)(m0 + row) * 1024 + k0 + sch * 8,
                     As + (size_t)(w * 256 + q * 64) * 8);
        }
        #pragma unroll
        for (int q = 0; q < WQ; q++) {
            const int cid = cid0 + q * 64;
            const int row = cid >> 3;
            const int sch = (cid & 7) ^ (row & 7);
            gl_lds16(W + (size_t)(n0 + row) * 1024 + k0 + sch * 8,
                     Bs + (size_t)(w * (N64 ? 128 : 256) + q * 64) * 8);
        }
        __syncthreads();
        #pragma unroll
        for (int ks = 0; ks < 64; ks += 32) {
            const int cbase = (ks >> 3) + quad;
            const int sw = col16 & 7;
            short8 a[4], b[NJ];
            #pragma unroll
            for (int i = 0; i < 4; i++) {
                const int row = wm * 64 + i * 16 + col16;
                a[i] = *(const short8*)(As + row * 64 + ((cbase ^ sw) << 3));
            }
            #pragma unroll
            for (int j = 0; j < NJ; j++) {
                const int row = wn * (NT / 2) + j * 16 + col16;
                b[j] = *(const short8*)(Bs + row * 64 + ((cbase ^ sw) << 3));
            }
            #pragma unroll
            for (int i = 0; i < 4; i++)
                #pragma unroll
                for (int j = 0; j < NJ; j++)
                    acc[i][j] = __builtin_amdgcn_mfma_f32_16x16x32_bf16(b[j], a[i], acc[i][j], 0, 0, 0);
        }
        __syncthreads();
    }

    #pragma unroll
    for (int i = 0; i < 4; i++) {
        const int m = m0 + wm * 64 + i * 16 + col16;
        #pragma unroll
        for (int j = 0; j < NJ; j++) {
            const int nb = n0 + wn * (NT / 2) + j * 16 + quad * 4;
            const float4 bv4 = *(const float4*)(bias + nb);
            const float v0 = acc[i][j][0] + bv4.x;
            const float v1 = acc[i][j][1] + bv4.y;
            const float v2 = acc[i][j][2] + bv4.z;
            const float v3 = acc[i][j][3] + bv4.w;
            if constexpr (OUT_F32) {
                *(float4*)((float*)Out + (size_t)m * 1024 + nb) = float4{v0, v1, v2, v3};
            } else {
                union { __hip_bfloat162 h[2]; unsigned long long u; } pk2;
                pk2.h[0] = __float22bfloat162_rn(float2{v0, v1});
                pk2.h[1] = __float22bfloat162_rn(float2{v2, v3});
                *(unsigned long long*)((ushortT*)Out + (size_t)m * 1024 + nb) = pk2.u;
            }
        }
    }
}

// ---------------------------------------------------------------------------
// attn v15: 32x32x16 MFMA, paired-wave key-split, QBLK=128, 8 waves (512 thr).
// Wave w = (qgrp = w>>1, kh = w&1): 32 queries (qgrp*32 + l31), kh-half of
// each 64-key tile. Per wave-tile: 4 ak + 4 av ds_read_b128 for 32q x 32k
// -> 8 B per q*k, HALF of v14's 16 (LDS-pipe was the binding resource).
// Shell identical to v14: grid 512 = 32 slices x 16 p-tiles, u/u+32 pairing
// (p, 15-p) -> 34 tiles/CU const, 2 blocks/CU = 16 waves/CU.
// Fragment math verbatim from v13 (refcheck-passed r3):
//   A/B: m(or n)=l&31, k=(l>>5)*8+j; C/D: col=l&31, row=(r&3)+8*(r>>2)+4*(l>>5);
//   off[a][b] = (a*32+l31)*64 + ((((b<<1)+h)^(lane&7))<<3); mask key =
//   a*32+(r&3)+((r>>2)<<3)+4*h; sp/permlane32 P-frags; C-write dt*32+8rq+4h.
// Pair-combine: partner waves (w, w^1) sum Oacc+l via LDS (33 f32/lane,
// stride 33 -> conflict-free); kh==0 writes. LDS 40 KB (2 blocks/CU ok).
// ---------------------------------------------------------------------------
__global__ __launch_bounds__(512, 4) void attn(
    const ushortT* __restrict__ Qb, const ushortT* __restrict__ Kb,
    const ushortT* __restrict__ VT, ushortT* __restrict__ Cb)
{
    __shared__ __align__(16) ushortT lds[20480];   // 40 KB

    const int t = threadIdx.x;             // 0..511
    const int bid = blockIdx.x;            // 0..511
    const int xcd = bid & 7;
    const int u = bid >> 3;                // 0..63
    const int s = xcd * 4 + (u & 3);       // slice 0..31
    const int x4 = u >> 2;                 // 0..15
    const int p = (x4 < 8) ? x4 : 23 - x4; // CU pair {a, a+8}: 34 tiles const
    const int bb = s >> 4, g = (s >> 3) & 1, mh = s & 7;

    const int w = t >> 6, lane = t & 63;
    const int l31 = lane & 31, h = lane >> 5;
    const int qgrp = w >> 1, kh = w & 1;

    const size_t baseoff = (size_t)bb * 2048 * 1024 + (size_t)g * 512;
    const size_t vtbase  = (size_t)s * 64 * 2048;
    const int i0 = mh * 2048 + p * 128;
    const int ntile = 2 * p + 2;
    const int qloc = qgrp * 32 + l31;      // 0..127

    // Q B-frags in registers (Q pre-scaled by KL): d = dc*16 + h*8 + (0..7)
    short8 qreg[4];
    {
        const int i = i0 + qloc;
        const ushortT* ptr = Qb + baseoff + (size_t)(i >> 3) * 1024 + (i & 7) * 64;
        #pragma unroll
        for (int dc = 0; dc < 4; dc++)
            qreg[dc] = *(const short8*)(ptr + dc * 16 + h * 8);
    }

    // fragment read offsets (elements), shared form for K and V tiles (v13)
    int off[2][4];
    #pragma unroll
    for (int a = 0; a < 2; a++)
        #pragma unroll
        for (int b = 0; b < 4; b++)
            off[a][b] = (a * 32 + l31) * 64 + ((((b << 1) + h) ^ (lane & 7)) << 3);

    // staging (same as v14): 1 K-load + 1 V-load per thread;
    // row = t>>3 (0..63), chunk = t&7, sch = chunk^(row&7).
    const int row = t >> 3;
    const int sch = (t & 7) ^ (row & 7);
    const int jr = mh * 2048 + row;        // kt=0 K packed row
    const ushortT* gk = Kb + baseoff + (size_t)(jr >> 3) * 1024 + (jr & 7) * 64 + sch * 8;
    const ushortT* gv = VT + vtbase + (size_t)row * 2048 + sch * 8;
    const int sdK = w * 512;               // wave-uniform dest offset (elems)

    auto stage = [&](int sb) {
        gl_lds16(gk, lds + sb + sdK);
        gl_lds16(gv, lds + sb + 8192 + sdK);
        gk += 8192; gv += 64;
    };

    float l4[4] = {0.f, 0.f, 0.f, 0.f};
    floatx16 Oacc[2];
    Oacc[0] = (floatx16)0.0f; Oacc[1] = (floatx16)0.0f;

    stage(0);                              // prologue fills buffer 0
    int sb = 4096;                         // next stage target
    int sbR = 0;                           // current read buffer
    #pragma unroll 1
    for (int kt = 0; kt < ntile; ++kt) {
        __syncthreads();                   // vmcnt drained -> read buffer ready
        if (kt < ntile - 1) { stage(sb); sb ^= 4096; }

        // S^T = K * Q^T  (this wave: 32 keys (kh half) x 32 queries)
        floatx16 sc = (floatx16)0.0f;
        __builtin_amdgcn_s_setprio(1);
        #pragma unroll
        for (int dc = 0; dc < 4; dc++) {
            const short8 ak = *(const short8*)(lds + sbR + off[kh][dc]);
            sc = __builtin_amdgcn_mfma_f32_32x32x16_bf16(ak, qreg[dc], sc, 0, 0, 0);
        }
        __builtin_amdgcn_s_setprio(0);

        const int dk = kt - 2 * p;         // causal region: last two tiles
        if (dk >= 0) {
            const int qe = qloc - 64 * dk;
            #pragma unroll
            for (int r = 0; r < 16; r++) {
                const int key = kh * 32 + (r & 3) + ((r >> 2) << 3) + 4 * h;
                if (key > qe) sc[r] = -1e30f;
            }
        }

        // no-max softmax: p = exp2(s); 4 independent l chains; pack bf16 pairs
        unsigned sp[8];
        #pragma unroll
        for (int i2 = 0; i2 < 8; i2++) {
            const float p0 = __builtin_amdgcn_exp2f(sc[2 * i2]);
            const float p1 = __builtin_amdgcn_exp2f(sc[2 * i2 + 1]);
            l4[(2 * i2) & 3] += p0;
            l4[(2 * i2 + 1) & 3] += p1;
            union { __hip_bfloat162 hh; unsigned uu; } pk;
            pk.hh = __float22bfloat162_rn(float2{p0, p1});
            sp[i2] = pk.uu;
        }

        // O^T += V^T * P^T over this wave's 32 keys (kcg = kh*2 + kc)
        #pragma unroll
        for (int kc = 0; kc < 2; kc++) {
            const uintx2 s0 = __builtin_amdgcn_permlane32_swap(
                sp[4 * kc + 0], sp[4 * kc + 2], false, false);
            const uintx2 s1 = __builtin_amdgcn_permlane32_swap(
                sp[4 * kc + 1], sp[4 * kc + 3], false, false);
            union { unsigned uu[4]; short8 ss; } bp;
            bp.uu[0] = s0.x; bp.uu[1] = s1.x; bp.uu[2] = s0.y; bp.uu[3] = s1.y;
            const int kcg = kh * 2 + kc;
            __builtin_amdgcn_s_setprio(1);
            #pragma unroll
            for (int dt = 0; dt < 2; dt++) {
                const short8 av = *(const short8*)(lds + sbR + 8192 + off[dt][kcg]);
                Oacc[dt] = __builtin_amdgcn_mfma_f32_32x32x16_bf16(av, bp.ss, Oacc[dt], 0, 0, 0);
            }
            __builtin_amdgcn_s_setprio(0);
        }

        sbR ^= 4096;                       // flip read buffer
    }

    // local l: lanes l and l+32 hold halves of this wave's 32-key sum
    float l_s = (l4[0] + l4[1]) + (l4[2] + l4[3]);
    l_s += __shfl_xor(l_s, 32);

    // pair-combine (w, w^1) via LDS: 33 f32/lane, stride 33 (conflict-free)
    __syncthreads();                       // all tile reads done; LDS reusable
    float* cb = (float*)lds;
    const int ci = (qgrp * 64 + lane) * 33;
    if (kh == 1) {
        #pragma unroll
        for (int dt = 0; dt < 2; dt++)
            #pragma unroll
            for (int r = 0; r < 16; r++) cb[ci + dt * 16 + r] = Oacc[dt][r];
        cb[ci + 32] = l_s;
    }
    __syncthreads();
    if (kh == 0) {
        #pragma unroll
        for (int dt = 0; dt < 2; dt++)
            #pragma unroll
            for (int r = 0; r < 16; r++) Oacc[dt][r] += cb[ci + dt * 16 + r];
        l_s += cb[ci + 32];
        const float inv = 1.0f / l_s;
        const int i = i0 + qloc;
        ushortT* dst = Cb + baseoff + (size_t)(i >> 3) * 1024 + (i & 7) * 64;
        #pragma unroll
        for (int dt = 0; dt < 2; dt++)
            #pragma unroll
            for (int rq = 0; rq < 4; rq++) {
                union { __hip_bfloat162 hh[2]; unsigned long long uu; } pk2;
                pk2.hh[0] = __float22bfloat162_rn(
                    float2{Oacc[dt][4 * rq + 0] * inv, Oacc[dt][4 * rq + 1] * inv});
                pk2.hh[1] = __float22bfloat162_rn(
                    float2{Oacc[dt][4 * rq + 2] * inv, Oacc[dt][4 * rq + 3] * inv});
                *(unsigned long long*)(dst + dt * 32 + 8 * rq + 4 * h) = pk2.uu;
            }
    }
}

extern "C" void kernel_launch(void* const* d_in, const int* in_sizes, int n_in,
                              void* d_out, int out_size, void* d_ws, size_t ws_size,
                              hipStream_t stream)
{
    const float* x  = (const float*)d_in[0];
    const float* Wq = (const float*)d_in[1];
    const float* bq = (const float*)d_in[2];
    const float* Wk = (const float*)d_in[3];
    const float* bk = (const float*)d_in[4];
    const float* Wv = (const float*)d_in[5];
    const float* bv = (const float*)d_in[6];
    const float* Wo = (const float*)d_in[7];
    const float* bo = (const float*)d_in[8];

    const size_t M1 = (size_t)1024 * 1024;
    ushortT* Wb  = (ushortT*)d_ws;            // Wq|Wk|Wv|Wo bf16, 8 MB
    ushortT* xb  = Wb + 4 * M1;               // 8 MB
    ushortT* Qb  = xb + 4 * M1;               // 8 MB; reused as Cb
    ushortT* Kb  = Qb + 4 * M1;               // 8 MB
    ushortT* VTb = Wb + 16 * M1;              // 8 MB @ +32MB (ws ~256 MiB)
    ushortT* Cb  = Qb;

    dim3 blk(256);
    cvt_bf16<<<dim3(4096), blk, 0, stream>>>(x, Wq, Wk, Wv, Wo, xb, Wb);
    gemm_qkv_8p<<<dim3(192), dim3(512), 0, stream>>>(
        xb, Wb, bq, bk, bv, Qb, Kb, VTb);
    attn<<<dim3(512), dim3(512), 0, stream>>>(Qb, Kb, VTb, Cb);
    gemm_lds<true, true><<<dim3(16, 32), blk, 0, stream>>>(
        Cb, Wb + 3 * M1, bo, bo, bo, d_out, d_out, d_out);
}

// Round 13
// 176.485 us; speedup vs baseline: 1.1087x; 1.1087x over previous
//
#include <hip/hip_runtime.h>
#include <hip/hip_bf16.h>

// MicroHeadAttention on MI355X (gfx950). fp32 in / fp32 out, bf16 MFMA internally.
// Pipeline: [cvt fp32->bf16] -> [QKV gemm 256x256 8-phase, Q pre-scaled by KL,
//            V written directly transposed via LDS repack (transpose_v fused)]
//        -> [attn v14: QBLK=128 via 8-wave blocks, register-P softmax]
//        -> [out-proj gemm 128x64].
// Scramble (derived from the proven transpose_v read side):
//   C[m][n] of the V gemm = V(b=m>>11, mh=(m>>8)&7, g=n>>9,
//                             pos=((m&255)<<3)|((n&511)>>6), d=n&63).
// Workspace (>=64 MB; harness poison fill shows ~256 MiB):
//   Wb(8) | xb(8) | Qb(8, reused as Cb) | Kb(8) | VT(8 @ +32MB).
typedef unsigned short ushortT;
typedef __attribute__((ext_vector_type(8))) short short8;
typedef __attribute__((ext_vector_type(4))) float floatx4;
typedef __attribute__((ext_vector_type(2))) unsigned int uintx2;

__device__ inline ushortT f2bf(float f) {
    union { float f; unsigned int i; } v; v.f = f;
    unsigned int x = v.i;
    return (ushortT)((x + 0x7fffu + ((x >> 16) & 1u)) >> 16);  // RNE
}

__device__ inline void gl_lds16(const ushortT* g, ushortT* lds) {
    __builtin_amdgcn_global_load_lds(
        (const __attribute__((address_space(1))) unsigned int*)g,
        (__attribute__((address_space(3))) unsigned int*)lds, 16, 0, 0);
}

// ---------------------------------------------------------------------------
// cvt: x (4M f32) -> xb bf16; Wq,Wk,Wv,Wo (1M each) -> Wb stacked bf16.
// ---------------------------------------------------------------------------
__global__ __launch_bounds__(256) void cvt_bf16(
    const float* __restrict__ x,
    const float* __restrict__ Wq, const float* __restrict__ Wk,
    const float* __restrict__ Wv, const float* __restrict__ Wo,
    ushortT* __restrict__ xb, ushortT* __restrict__ Wb)
{
    const unsigned tid = blockIdx.x * 256 + threadIdx.x;
    const size_t e = (size_t)tid * 8;
    const float* src;
    ushortT* dst;
    size_t off;
    if (e < (size_t)(4u << 20)) { src = x; dst = xb; off = e; }
    else {
        const size_t r = e - (size_t)(4u << 20);
        const int wsel = (int)(r >> 20);
        off = r & 0xFFFFFu;
        src = (wsel == 0) ? Wq : (wsel == 1) ? Wk : (wsel == 2) ? Wv : Wo;
        dst = Wb + ((size_t)wsel << 20);
    }
    const float4 f0 = ((const float4*)(src + off))[0];
    const float4 f1 = ((const float4*)(src + off))[1];
    union { __hip_bfloat162 h[4]; uint4 u; } pk;
    pk.h[0] = __float22bfloat162_rn(float2{f0.x, f0.y});
    pk.h[1] = __float22bfloat162_rn(float2{f0.z, f0.w});
    pk.h[2] = __float22bfloat162_rn(float2{f1.x, f1.y});
    pk.h[3] = __float22bfloat162_rn(float2{f1.z, f1.w});
    *(uint4*)(dst + off) = pk.u;
}

// ---------------------------------------------------------------------------
// gemm_qkv_8p: C[m,n] = (sum_k A[m,k]*W[n,k] + bias[n]) * oscale, bf16 out.
// 256x256 tile, BK=64, 512 thr, T3+T4+T5 schedule, 128 KB LDS.
// mat==2 (V): epilogue repacks acc via LDS Lv[d(64)][pi(1024)], pi=ml*4+wn,
// then streams uint2 runs to VT[slice][d][pos] (transpose_v fused).
// ---------------------------------------------------------------------------
__global__ __launch_bounds__(512, 2) void gemm_qkv_8p(
    const ushortT* __restrict__ A, const ushortT* __restrict__ Wst,
    const float* __restrict__ b0, const float* __restrict__ b1, const float* __restrict__ b2,
    ushortT* __restrict__ O0, ushortT* __restrict__ O1, ushortT* __restrict__ VT)
{
    __shared__ __align__(16) ushortT sm[65536];   // 128 KB

    const int t = threadIdx.x;
    const int bid = blockIdx.x;                    // 0..191
    const int wg = (bid & 7) * 24 + (bid >> 3);    // bijective XCD chunk swizzle
    const int mt = wg / 12;                        // 0..15
    const int nt = wg - mt * 12;                   // 0..11 (3 mats x 4 tiles)
    const int m0 = mt * 256;
    const int mat = nt >> 2;
    const int n0 = (nt & 3) * 256;
    const ushortT* W = Wst + ((size_t)mat << 20);
    const float* bias = (mat == 0) ? b0 : (mat == 1) ? b1 : b2;
    ushortT* Out     = (mat == 0) ? O0 : O1;       // mat 2 uses the VT path
    const float oscale = (mat == 0) ? 0.18033688f : 1.0f;   // 0.125*log2(e)

    const int w = t >> 6, lane = t & 63;
    const int wm = w >> 2, wn = w & 3;             // 2 x 4 wave grid
    const int col16 = lane & 15, quad = lane >> 4;
    const int c7 = col16 & 7;

    // fragment read offsets (elements); row&7 == col16&7 for all frag rows
    const int ko[2] = { ((0 + quad) ^ c7) << 3, ((4 + quad) ^ c7) << 3 };
    const int xbase = (wm * 128 + col16) * 64;     // x rows (MFMA B-operand)
    const int wbase = (wn * 64 + col16) * 64;      // W rows (MFMA A-operand)

    // staging: cid = q*512 + t -> row q*64+(t>>3), chunk t&7, sch = chunk^(row&7)
    const int trow = t >> 3;
    const int sch = (t & 7) ^ (trow & 7);
    const ushortT* gA[4]; const ushortT* gB[4];
    #pragma unroll
    for (int q = 0; q < 4; q++) {
        gA[q] = A + (size_t)(m0 + q * 64 + trow) * 1024 + sch * 8;
        gB[q] = W + (size_t)(n0 + q * 64 + trow) * 1024 + sch * 8;
    }
    const int dst0 = (w << 6) * 8;                 // wave-uniform LDS dest base

    floatx4 acc[8][4];
    #pragma unroll
    for (int i = 0; i < 8; i++)
        #pragma unroll
        for (int j = 0; j < 4; j++) acc[i][j] = (floatx4)0.0f;

    auto issue8 = [&](const int ab, const int bb) {
        #pragma unroll
        for (int q = 0; q < 4; q++) {
            gl_lds16(gA[q], sm + ab + dst0 + q * 4096);
            gl_lds16(gB[q], sm + bb + dst0 + q * 4096);
            gA[q] += 64; gB[q] += 64;
        }
    };

    auto group = [&](const int ab, const int bb) {   // 4 phases over one K-tile
        short8 bw[4];
        #pragma unroll
        for (int ks = 0; ks < 2; ks++) {
            #pragma unroll
            for (int mh = 0; mh < 2; mh++) {
                short8 bx[4];
                if (mh == 0) {
                    #pragma unroll
                    for (int nf = 0; nf < 4; nf++)
                        bw[nf] = *(const short8*)(sm + bb + wbase + nf * 1024 + ko[ks]);
                }
                #pragma unroll
                for (int j = 0; j < 4; j++)
                    bx[j] = *(const short8*)(sm + ab + xbase + (mh * 4 + j) * 1024 + ko[ks]);
                __builtin_amdgcn_s_barrier();
                __builtin_amdgcn_s_setprio(1);
                #pragma unroll
                for (int j = 0; j < 4; j++)
                    #pragma unroll
                    for (int nf = 0; nf < 4; nf++)
                        acc[mh * 4 + j][nf] = __builtin_amdgcn_mfma_f32_16x16x32_bf16(
                            bw[nf], bx[j], acc[mh * 4 + j][nf], 0, 0, 0);
                __builtin_amdgcn_s_setprio(0);
                __builtin_amdgcn_s_barrier();
            }
        }
    };

    issue8(0, 16384);            // tile 0 -> buf0
    issue8(32768, 49152);        // tile 1 -> buf1

    #pragma unroll 1
    for (int it = 0; it < 7; ++it) {
        asm volatile("s_waitcnt vmcnt(8)" ::: "memory");   // tile 2it landed
        __builtin_amdgcn_s_barrier();
        group(0, 16384);
        issue8(0, 16384);                                  // tile 2it+2 -> buf0
        asm volatile("s_waitcnt vmcnt(8)" ::: "memory");   // tile 2it+1 landed
        __builtin_amdgcn_s_barrier();
        group(32768, 49152);
        issue8(32768, 49152);                              // tile 2it+3 -> buf1
    }
    asm volatile("s_waitcnt vmcnt(8)" ::: "memory");       // tile 14 landed
    __builtin_amdgcn_s_barrier();
    group(0, 16384);
    asm volatile("s_waitcnt vmcnt(0)" ::: "memory");       // tile 15 landed
    __builtin_amdgcn_s_barrier();
    group(32768, 49152);

    if (mat != 2) {
        // epilogue: D[n via quad*4+r, m via col16] (swapped-operand layout)
        #pragma unroll
        for (int mf = 0; mf < 8; mf++) {
            const int m = m0 + wm * 128 + mf * 16 + col16;
            #pragma unroll
            for (int nf = 0; nf < 4; nf++) {
                const int nb = n0 + wn * 64 + nf * 16 + quad * 4;
                const float4 bv4 = *(const float4*)(bias + nb);
                const float v0 = (acc[mf][nf][0] + bv4.x) * oscale;
                const float v1 = (acc[mf][nf][1] + bv4.y) * oscale;
                const float v2 = (acc[mf][nf][2] + bv4.z) * oscale;
                const float v3 = (acc[mf][nf][3] + bv4.w) * oscale;
                union { __hip_bfloat162 h[2]; unsigned long long u; } pk2;
                pk2.h[0] = __float22bfloat162_rn(float2{v0, v1});
                pk2.h[1] = __float22bfloat162_rn(float2{v2, v3});
                *(unsigned long long*)(Out + (size_t)m * 1024 + nb) = pk2.u;
            }
        }
    } else {
        // V epilogue: acc -> LDS Lv[d][pi], pi = ml*4 + wn, then uint2 runs.
        __syncthreads();                           // LDS dead after K-loop
        #pragma unroll
        for (int mf = 0; mf < 8; mf++) {
            const int ml = wm * 128 + mf * 16 + col16;
            const int pib = ml * 4 + wn;
            #pragma unroll
            for (int nf = 0; nf < 4; nf++) {
                const int dbase = nf * 16 + quad * 4;
                const float4 bv4 = *(const float4*)(bias + n0 + wn * 64 + dbase);
                sm[(dbase + 0) * 1024 + pib] = f2bf(acc[mf][nf][0] + bv4.x);
                sm[(dbase + 1) * 1024 + pib] = f2bf(acc[mf][nf][1] + bv4.y);
                sm[(dbase + 2) * 1024 + pib] = f2bf(acc[mf][nf][2] + bv4.z);
                sm[(dbase + 3) * 1024 + pib] = f2bf(acc[mf][nf][3] + bv4.w);
            }
        }
        __syncthreads();
        const int b2 = mt >> 3, mhh = mt & 7, gg = n0 >> 9;
        const int p0 = (n0 & 511) >> 6;
        ushortT* vbase = VT + (size_t)((b2 * 2 + gg) * 8 + mhh) * 131072 + p0;
        #pragma unroll
        for (int v = 0; v < 32; v++) {
            const int e = v * 512 + t;             // 0..16383 run index
            const int d = e >> 8;                  // 0..63
            const int runml = e & 255;             // 0..255
            const uint2 val = *(const uint2*)(sm + d * 1024 + runml * 4);
            *(uint2*)(vbase + d * 2048 + runml * 8) = val;
        }
    }
}

// ---------------------------------------------------------------------------
// gemm_lds (out-proj): C[m,n] = sum_k A[m,k]*W[n,k] + bias[n]. Tile 128 x 64,
// BK=64, 4 waves 2x2, MFMA operands swapped -> vectorized stores.
// ---------------------------------------------------------------------------
template <bool OUT_F32, bool N64>
__global__ __launch_bounds__(256) void gemm_lds(
    const ushortT* __restrict__ A, const ushortT* __restrict__ Wst,
    const float* __restrict__ b0, const float* __restrict__ b1, const float* __restrict__ b2,
    void* __restrict__ O0, void* __restrict__ O1, void* __restrict__ O2)
{
    constexpr int NT = N64 ? 64 : 128;
    constexpr int NJ = N64 ? 2 : 4;
    constexpr int WQ = N64 ? 2 : 4;
    __shared__ __align__(16) ushortT As[128 * 64];
    __shared__ __align__(16) ushortT Bs[NT * 64];
    const int t = threadIdx.x;
    const int m0 = blockIdx.y * 128;
    const int n0g = blockIdx.x * NT;
    const int mat = n0g >> 10;
    const int n0 = n0g & 1023;
    const ushortT* W = Wst + ((size_t)mat << 20);
    const float* bias = (mat == 0) ? b0 : (mat == 1) ? b1 : b2;
    void* Out        = (mat == 0) ? O0 : (mat == 1) ? O1 : O2;

    const int w = t >> 6, lane = t & 63;
    const int wm = w >> 1, wn = w & 1;
    const int col16 = lane & 15, quad = lane >> 4;

    floatx4 acc[4][NJ];
    for (int i = 0; i < 4; i++)
        for (int j = 0; j < NJ; j++) acc[i][j] = (floatx4)0.0f;

    const int cid0 = w * (N64 ? 128 : 256) + lane;

    for (int k0 = 0; k0 < 1024; k0 += 64) {
        #pragma unroll
        for (int q = 0; q < 4; q++) {
            const int cid = w * 256 + q * 64 + lane;
            const int row = cid >> 3;
            const int sch = (cid & 7) ^ (row & 7);
            gl_lds16(A + (size_t)(m0 + row) * 1024 + k0 + sch * 8,
                     As + (size_t)(w * 256 + q * 64) * 8);
        }
        #pragma unroll
        for (int q = 0; q < WQ; q++) {
            const int cid = cid0 + q * 64;
            const int row = cid >> 3;
            const int sch = (cid & 7) ^ (row & 7);
            gl_lds16(W + (size_t)(n0 + row) * 1024 + k0 + sch * 8,
                     Bs + (size_t)(w * (N64 ? 128 : 256) + q * 64) * 8);
        }
        __syncthreads();
        #pragma unroll
        for (int ks = 0; ks < 64; ks += 32) {
            const int cbase = (ks >> 3) + quad;
            const int sw = col16 & 7;
            short8 a[4], b[NJ];
            #pragma unroll
            for (int i = 0; i < 4; i++) {
                const int row = wm * 64 + i * 16 + col16;
                a[i] = *(const short8*)(As + row * 64 + ((cbase ^ sw) << 3));
            }
            #pragma unroll
            for (int j = 0; j < NJ; j++) {
                const int row = wn * (NT / 2) + j * 16 + col16;
                b[j] = *(const short8*)(Bs + row * 64 + ((cbase ^ sw) << 3));
            }
            #pragma unroll
            for (int i = 0; i < 4; i++)
                #pragma unroll
                for (int j = 0; j < NJ; j++)
                    acc[i][j] = __builtin_amdgcn_mfma_f32_16x16x32_bf16(b[j], a[i], acc[i][j], 0, 0, 0);
        }
        __syncthreads();
    }

    #pragma unroll
    for (int i = 0; i < 4; i++) {
        const int m = m0 + wm * 64 + i * 16 + col16;
        #pragma unroll
        for (int j = 0; j < NJ; j++) {
            const int nb = n0 + wn * (NT / 2) + j * 16 + quad * 4;
            const float4 bv4 = *(const float4*)(bias + nb);
            const float v0 = acc[i][j][0] + bv4.x;
            const float v1 = acc[i][j][1] + bv4.y;
            const float v2 = acc[i][j][2] + bv4.z;
            const float v3 = acc[i][j][3] + bv4.w;
            if constexpr (OUT_F32) {
                *(float4*)((float*)Out + (size_t)m * 1024 + nb) = float4{v0, v1, v2, v3};
            } else {
                union { __hip_bfloat162 h[2]; unsigned long long u; } pk2;
                pk2.h[0] = __float22bfloat162_rn(float2{v0, v1});
                pk2.h[1] = __float22bfloat162_rn(float2{v2, v3});
                *(unsigned long long*)((ushortT*)Out + (size_t)m * 1024 + nb) = pk2.u;
            }
        }
    }
}

// ---------------------------------------------------------------------------
// attn v14: QBLK=128 via 8-wave (512-thr) blocks. Each wave = v11's role
// (16 queries, 2 Q-frags, register-P softmax via permlane swaps); 8 waves
// share one K/V staging stream -> per-CU K/V delivery halves vs v11 while
// occupancy stays 16 waves/CU (2 blocks/CU). Grid 512 = 32 slices x 16
// p-tiles; blocks u and u+32 share a CU -> p and 15-p pair (34 tiles const).
// LDS 32 KB: K dbuf @0/@4096, V dbuf @8192/@12288 (elements).
// Stage: 2 gl_lds16/thread (K row t>>3, V row t>>3), XOR chunk swizzle.
// Causal on last two tiles: qe = qloc - 64*(kt-2p).
// ---------------------------------------------------------------------------
__global__ __launch_bounds__(512, 4) void attn(
    const ushortT* __restrict__ Qb, const ushortT* __restrict__ Kb,
    const ushortT* __restrict__ VT, ushortT* __restrict__ Cb)
{
    __shared__ __align__(16) ushortT lds[16384];   // 32 KB

    const int t = threadIdx.x;             // 0..511
    const int bid = blockIdx.x;            // 0..511
    const int xcd = bid & 7;
    const int u = bid >> 3;                // 0..63
    const int s = xcd * 4 + (u & 3);       // slice 0..31
    const int x4 = u >> 2;                 // 0..15
    const int p = (x4 < 8) ? x4 : 23 - x4; // CU pair {a, a+8}: 34 tiles const
    const int bb = s >> 4, g = (s >> 3) & 1, mh = s & 7;

    const int w = t >> 6, lane = t & 63;
    const int col16 = lane & 15, quad = lane >> 4;

    const size_t baseoff = (size_t)bb * 2048 * 1024 + (size_t)g * 512;
    const size_t vtbase  = (size_t)s * 64 * 2048;
    const int i0 = mh * 2048 + p * 128;
    const int ntile = 2 * p + 2;
    const int qloc = w * 16 + col16;       // 0..127
    const int c7 = col16 & 7;

    // Q fragments in registers (B-operand layout); Q pre-scaled by KL
    short8 qreg[2];
    {
        const int i = i0 + qloc;
        const ushortT* ptr = Qb + baseoff + (size_t)(i >> 3) * 1024 + (i & 7) * 64;
        qreg[0] = *(const short8*)(ptr + quad * 8);
        qreg[1] = *(const short8*)(ptr + 32 + quad * 8);
    }

    // hoisted K/V read offsets (element units); identical across waves
    int kbo[2];
    kbo[0] = col16 * 64 + (((0 + quad) ^ c7) << 3);
    kbo[1] = col16 * 64 + (((4 + quad) ^ c7) << 3);

    // staging pointers (advance by constants per kt): 1 K-load + 1 V-load per
    // thread; row = t>>3 (0..63), chunk = t&7, sch = chunk^(row&7).
    const int row = t >> 3;
    const int sch = (t & 7) ^ (row & 7);
    const int jr = mh * 2048 + row;        // kt=0 K packed row
    const ushortT* gk = Kb + baseoff + (size_t)(jr >> 3) * 1024 + (jr & 7) * 64 + sch * 8;
    const ushortT* gv = VT + vtbase + (size_t)row * 2048 + sch * 8;
    const int sdK = w * 512;               // wave-uniform dest offset (elems)

    auto stage = [&](int sb) {
        gl_lds16(gk, lds + sb + sdK);
        gl_lds16(gv, lds + sb + 8192 + sdK);
        gk += 8192; gv += 64;
    };

    float l4[4] = {0.f, 0.f, 0.f, 0.f};
    floatx4 Oacc[4];
    for (int c = 0; c < 4; c++) Oacc[c] = (floatx4)0.0f;

    stage(0);                              // prologue fills buffer 0
    int sb = 4096;                         // next stage target
    #pragma unroll 1
    for (int kt = 0; kt < ntile; ++kt) {
        __syncthreads();                   // vmcnt drained -> read buffer ready
        if (kt < ntile - 1) { stage(sb); sb ^= 4096; }

        // S^T = K * Q^T (Q carries the KL scale already)
        floatx4 sc[4];
        for (int c = 0; c < 4; c++) sc[c] = (floatx4)0.0f;
        #pragma unroll
        for (int h = 0; h < 2; h++) {
            const short8 bq = qreg[h];
            #pragma unroll
            for (int c = 0; c < 4; c++) {
                const short8 ak = *(const short8*)(lds + kbo[h] + c * 1024);
                sc[c] = __builtin_amdgcn_mfma_f32_16x16x32_bf16(ak, bq, sc[c], 0, 0, 0);
            }
        }

        const int dk = kt - 2 * p;         // causal region: last two tiles
        if (dk >= 0) {
            const int qe = qloc - 64 * dk;
            #pragma unroll
            for (int c = 0; c < 4; c++)
                #pragma unroll
                for (int r = 0; r < 4; r++)
                    if ((c * 16 + quad * 4 + r) > qe) sc[c][r] = -1e30f;
        }

        // no-max softmax: p = exp2(s); independent l chains; pack to bf16 pairs
        unsigned pw[4][2];
        #pragma unroll
        for (int c = 0; c < 4; c++) {
            float pv0 = __builtin_amdgcn_exp2f(sc[c][0]);
            float pv1 = __builtin_amdgcn_exp2f(sc[c][1]);
            float pv2 = __builtin_amdgcn_exp2f(sc[c][2]);
            float pv3 = __builtin_amdgcn_exp2f(sc[c][3]);
            l4[0] += pv0; l4[1] += pv1; l4[2] += pv2; l4[3] += pv3;
            union { __hip_bfloat162 h; unsigned u; } a, b;
            a.h = __float22bfloat162_rn(float2{pv0, pv1});
            b.h = __float22bfloat162_rn(float2{pv2, pv3});
            pw[c][0] = a.u; pw[c][1] = b.u;
        }

        // O^T += V^T * P^T; P^T B-frags built via permlane swaps
        #pragma unroll
        for (int h = 0; h < 2; h++) {
            unsigned dw[4];
            #pragma unroll
            for (int uu = 0; uu < 2; uu++) {
                uintx2 s32 = __builtin_amdgcn_permlane32_swap(pw[2 * h][uu], pw[2 * h + 1][uu], false, false);
                uintx2 s16 = __builtin_amdgcn_permlane16_swap(s32.x, s32.y, false, false);
                dw[uu] = s16.x; dw[2 + uu] = s16.y;
            }
            union { unsigned u2[4]; short8 s2; } bpu;
            bpu.u2[0] = dw[0]; bpu.u2[1] = dw[1]; bpu.u2[2] = dw[2]; bpu.u2[3] = dw[3];
            const short8 bp = bpu.s2;
            #pragma unroll
            for (int c = 0; c < 4; c++) {
                const short8 av = *(const short8*)(lds + kbo[h] + 8192 + c * 1024);
                Oacc[c] = __builtin_amdgcn_mfma_f32_16x16x32_bf16(av, bp, Oacc[c], 0, 0, 0);
            }
        }

        kbo[0] ^= 4096; kbo[1] ^= 4096;    // flip read buffer
    }

    // combine l chains, then cross-lane reduce (quads of same col16 = same query)
    float l_s = (l4[0] + l4[1]) + (l4[2] + l4[3]);
    l_s += __shfl_xor(l_s, 16);
    l_s += __shfl_xor(l_s, 32);

    {
        const int i = i0 + qloc;
        const float inv = 1.0f / l_s;
        ushortT* dst = Cb + baseoff + (size_t)(i >> 3) * 1024 + (i & 7) * 64;
        #pragma unroll
        for (int c = 0; c < 4; c++) {
            union { __hip_bfloat162 h[2]; unsigned long long u2; } pk2;
            pk2.h[0] = __float22bfloat162_rn(float2{Oacc[c][0] * inv, Oacc[c][1] * inv});
            pk2.h[1] = __float22bfloat162_rn(float2{Oacc[c][2] * inv, Oacc[c][3] * inv});
            *(unsigned long long*)(dst + c * 16 + quad * 4) = pk2.u2;
        }
    }
}

extern "C" void kernel_launch(void* const* d_in, const int* in_sizes, int n_in,
                              void* d_out, int out_size, void* d_ws, size_t ws_size,
                              hipStream_t stream)
{
    const float* x  = (const float*)d_in[0];
    const float* Wq = (const float*)d_in[1];
    const float* bq = (const float*)d_in[2];
    const float* Wk = (const float*)d_in[3];
    const float* bk = (const float*)d_in[4];
    const float* Wv = (const float*)d_in[5];
    const float* bv = (const float*)d_in[6];
    const float* Wo = (const float*)d_in[7];
    const float* bo = (const float*)d_in[8];

    const size_t M1 = (size_t)1024 * 1024;
    ushortT* Wb  = (ushortT*)d_ws;            // Wq|Wk|Wv|Wo bf16, 8 MB
    ushortT* xb  = Wb + 4 * M1;               // 8 MB
    ushortT* Qb  = xb + 4 * M1;               // 8 MB; reused as Cb
    ushortT* Kb  = Qb + 4 * M1;               // 8 MB
    ushortT* VTb = Wb + 16 * M1;              // 8 MB @ +32MB (ws ~256 MiB)
    ushortT* Cb  = Qb;

    dim3 blk(256);
    cvt_bf16<<<dim3(4096), blk, 0, stream>>>(x, Wq, Wk, Wv, Wo, xb, Wb);
    gemm_qkv_8p<<<dim3(192), dim3(512), 0, stream>>>(
        xb, Wb, bq, bk, bv, Qb, Kb, VTb);
    attn<<<dim3(512), dim3(512), 0, stream>>>(Qb, Kb, VTb, Cb);
    gemm_lds<true, true><<<dim3(16, 32), blk, 0, stream>>>(
        Cb, Wb + 3 * M1, bo, bo, bo, d_out, d_out, d_out);
}